// Round 5
// baseline (244.354 us; speedup 1.0000x reference)
//
#include <hip/hip_runtime.h>
#include <hip/hip_bf16.h>

// ---------------------------------------------------------------------------
// MonotonicAlignmentSearch R17: cut CU->L2 request traffic ~4x (the real
// bottleneck per R14 arithmetic: ~390 MB of L2-side reads at ~6 TB/s).
//  - convs: block = 16ch x 256bt (8 waves x 32bt, full-K in regs, no LDS);
//    weight panel shared by all 8 waves (read once: 6 MB vs 48 MB); taps
//    interleaved per k-chunk so the +-1-row overlap L1-hits.
//  - tp/ap GEMM: 128x128 LDS-staged block tiles (wave 32x64, K-step 64,
//    padded [128][72] LDS): ap 128->32 MB, tp 32->8 MB.
//  - logits: 8 bt rows per block (acc[8]): apT4 re-reads 64->32 MB.
// B=2, TT=128, TA=512, H=1024.
// ---------------------------------------------------------------------------

typedef __bf16 bf16_t;
typedef __bf16 bf16x8 __attribute__((ext_vector_type(8)));
typedef __bf16 bf16x4 __attribute__((ext_vector_type(4)));
typedef float  f32x4  __attribute__((ext_vector_type(4)));
typedef _Float16 f16_t;
typedef _Float16 f16x2 __attribute__((ext_vector_type(2)));
typedef _Float16 f16x4 __attribute__((ext_vector_type(4)));

#define EPSV 1e-5f

// ---- workspace offsets (bytes) — no overlays, ~26.3 MB << 256 MB ws -------
#define OFF_TEXTBF   0u          //  524288  bf16 text [256][1024]
#define OFF_AUDIOBF  524288u     // 2097152  bf16 audio [1024][1024]
#define OFF_W1TOP    2621440u    // 2097152  bf16 W1topT [1024 d][1024 h]
#define OFF_W1BOT    4718592u    // 2097152  bf16 W1botT [1024 d][1024 h]
#define OFF_WC1      6815744u    // 6291456  bf16 Wc1 [3][1024][1024]
#define OFF_WC2      13107200u   // 6291456  bf16 Wc2 [3][1024][1024] (g-scaled)
#define OFF_TP       19398656u   //  524288  f16 tp [256 bt][1024 d] (bias folded)
#define OFF_W2F      19922944u   //    2048  f16 w2 [1024]
#define OFF_APT      20447232u   // 2097152  f16 apT4 [256 hq][1024 ba][4]
#define OFF_XP0      22544384u   //  532480  bf16 xp0 [2][130][1024]
#define OFF_XP1      23076864u   //  532480  bf16 xp1 [2][130][1024] (raw relu)
#define OFF_Y2       23609344u   //  524288  bf16 y2 [256][1024] (pre-GN2)
#define OFF_BST1     24133632u   //    4096  f32 bstat1 [512][2] (conv1 partials)
#define OFF_BST2     24137728u   //    4096  f32 bstat2 [512][2] (conv2 partials)
#define OFF_LP       24141824u   // 2097152  f32 lp [4 hc][256 bt][512 a]
#define OFF_SG       26238976u   //   12288  f32 Sg [1024][3]  (sum_c w2*g)
#define OFF_SB       26251264u   //   12288  f32 Sb [1024][3]  (sum_c w2*beta)
#define OFF_SGF      26263552u   //    4096  f32 SgF [1024] (full tap sum)
#define OFF_SBF      26267648u   //    4096  f32 SbF [1024]

// ---------------------------------------------------------------------------
// prep: [0,1280) cvt activations; [1280,3328) w1 transpose-cast;
// [3328,5376) conv-weight cvt (wc2 g-scaled + Sg/Sb/SgF/SbF sums);
// 5376: zero pads + w2->f16.
// ---------------------------------------------------------------------------
__global__ __launch_bounds__(256) void prep_k(
    const float* __restrict__ text, const float* __restrict__ audio,
    const float* __restrict__ w1,
    const float* __restrict__ w1c, const float* __restrict__ w2c,
    const float* __restrict__ w2,
    const float* __restrict__ g1, const float* __restrict__ b1g,
    bf16_t* __restrict__ text_bf, bf16_t* __restrict__ xp0,
    bf16_t* __restrict__ audio_bf,
    bf16_t* __restrict__ topT, bf16_t* __restrict__ botT,
    bf16_t* __restrict__ wc1, bf16_t* __restrict__ wc2,
    bf16_t* __restrict__ xp1, f16_t* __restrict__ w2f,
    float* __restrict__ Sg, float* __restrict__ Sb,
    float* __restrict__ SgF, float* __restrict__ SbF)
{
    __shared__ float tile[32][33];
    const int bid = blockIdx.x;
    if (bid < 1280) {
        const int e = (bid * 256 + threadIdx.x) * 4;   // 1310720 total
        if (e < 262144) {
            float4 v = *(const float4*)&text[e];
            bf16x4 o; o[0] = (bf16_t)v.x; o[1] = (bf16_t)v.y; o[2] = (bf16_t)v.z; o[3] = (bf16_t)v.w;
            *(bf16x4*)&text_bf[e] = o;
            const int bt = e >> 10, h = e & 1023;
            const int b = bt >> 7, t = bt & 127;
            *(bf16x4*)&xp0[(size_t)(b * 130 + 1 + t) * 1024 + h] = o;
        } else {
            const int ea = e - 262144;
            float4 v = *(const float4*)&audio[ea];
            bf16x4 o; o[0] = (bf16_t)v.x; o[1] = (bf16_t)v.y; o[2] = (bf16_t)v.z; o[3] = (bf16_t)v.w;
            *(bf16x4*)&audio_bf[ea] = o;
        }
    } else if (bid < 3328) {
        const int b2 = bid - 1280;
        const int bx = b2 & 31, by = b2 >> 5;          // (32, 64)
        const int tx = threadIdx.x & 31, ty = threadIdx.x >> 5;
        #pragma unroll
        for (int j = 0; j < 4; ++j)
            tile[ty + j * 8][tx] = w1[(size_t)(by * 32 + ty + j * 8) * 1024 + bx * 32 + tx];
        __syncthreads();
        bf16_t* out = (by < 32) ? topT : botT;
        const int hbase = (by & 31) * 32;
        #pragma unroll
        for (int j = 0; j < 4; ++j) {
            const int d = bx * 32 + ty + j * 8;
            out[(size_t)d * 1024 + hbase + tx] = (bf16_t)tile[tx][ty + j * 8];
        }
    } else if (bid < 5376) {
        int b2 = bid - 3328;
        const int is2 = (b2 >= 1024) ? 1 : 0;
        const float* w = is2 ? w2c : w1c;
        bf16_t* wc = is2 ? wc2 : wc1;
        b2 &= 1023;
        const int o = b2, i4 = threadIdx.x;            // one block per out-chan
        const float* src = w + (size_t)o * 3072 + i4 * 12;
        float4 v0 = *(const float4*)&src[0];
        float4 v1 = *(const float4*)&src[4];
        float4 v2 = *(const float4*)&src[8];
        const float f[12] = {v0.x, v0.y, v0.z, v0.w, v1.x, v1.y, v1.z, v1.w, v2.x, v2.y, v2.z, v2.w};
        float g4[4] = {1.f, 1.f, 1.f, 1.f}, bb4[4] = {0.f, 0.f, 0.f, 0.f};
        if (is2) {
            float4 gv = *(const float4*)&g1[i4 * 4];
            float4 bv = *(const float4*)&b1g[i4 * 4];
            g4[0] = gv.x; g4[1] = gv.y; g4[2] = gv.z; g4[3] = gv.w;
            bb4[0] = bv.x; bb4[1] = bv.y; bb4[2] = bv.z; bb4[3] = bv.w;
        }
        float sgr[3] = {0.f, 0.f, 0.f}, sbr[3] = {0.f, 0.f, 0.f};
        #pragma unroll
        for (int r = 0; r < 3; ++r) {
            bf16x4 o4;
            #pragma unroll
            for (int j = 0; j < 4; ++j) {
                const float wv = f[j * 3 + r];
                const float ws = wv * g4[j];
                sgr[r] += ws;
                sbr[r] += wv * bb4[j];
                o4[j] = (bf16_t)(is2 ? ws : wv);
            }
            *(bf16x4*)&wc[(size_t)r * 1048576 + (size_t)o * 1024 + i4 * 4] = o4;
        }
        if (is2) {
            #pragma unroll
            for (int off = 32; off > 0; off >>= 1) {
                #pragma unroll
                for (int r = 0; r < 3; ++r) {
                    sgr[r] += __shfl_xor(sgr[r], off);
                    sbr[r] += __shfl_xor(sbr[r], off);
                }
            }
            float* red = &tile[0][0];
            const int wid = threadIdx.x >> 6, lane = threadIdx.x & 63;
            if (lane == 0) {
                #pragma unroll
                for (int r = 0; r < 3; ++r) {
                    red[wid * 6 + r] = sgr[r];
                    red[wid * 6 + 3 + r] = sbr[r];
                }
            }
            __syncthreads();
            if (threadIdx.x < 6) {
                const float v = red[threadIdx.x] + red[6 + threadIdx.x]
                              + red[12 + threadIdx.x] + red[18 + threadIdx.x];
                if (threadIdx.x < 3) Sg[o * 3 + threadIdx.x] = v;
                else                 Sb[o * 3 + threadIdx.x - 3] = v;
                red[24 + threadIdx.x] = v;
            }
            __syncthreads();
            if (threadIdx.x == 0)      SgF[o] = red[24] + red[25] + red[26];
            else if (threadIdx.x == 1) SbF[o] = red[27] + red[28] + red[29];
        }
    } else {
        const int tid = threadIdx.x;
        const int rowmap[4] = {0, 129, 130, 259};
        const int f = tid * 16;
        const int r = f >> 10, w = f & 1023;
        bf16x8 z8 = (bf16x8)(bf16_t)0.0f;
        bf16_t* p0 = xp0 + (size_t)rowmap[r] * 1024 + w;
        bf16_t* p1 = xp1 + (size_t)rowmap[r] * 1024 + w;
        *(bf16x8*)p0 = z8; *(bf16x8*)(p0 + 8) = z8;
        *(bf16x8*)p1 = z8; *(bf16x8*)(p1 + 8) = z8;
        float4 wv = *(const float4*)&w2[tid * 4];
        f16x4 wo; wo[0] = (f16_t)wv.x; wo[1] = (f16_t)wv.y; wo[2] = (f16_t)wv.z; wo[3] = (f16_t)wv.w;
        *(f16x4*)&w2f[tid * 4] = wo;
    }
}

// ---------------------------------------------------------------------------
// helpers
// ---------------------------------------------------------------------------
__device__ __forceinline__ float wave_red_add(float v) {
    #pragma unroll
    for (int off = 32; off > 0; off >>= 1) v += __shfl_xor(v, off);
    return v;
}

// Full-K conv wave: 16 chans x 32 bt. Taps interleaved per k-chunk (the
// +-1-row overlap between taps lands in L1 within a few instructions).
// 9 independent loads then 6 MFMAs per chunk; 32 chunks.
__device__ __forceinline__ void conv_mfma_full(
    const bf16_t* __restrict__ Wc, const bf16_t* __restrict__ xp,
    int m0, int b, int tbase, int l, f32x4& acc0, f32x4& acc1)
{
    const int lm = l & 15, lk = (l >> 4) * 8;
    const bf16_t* aq = Wc + (size_t)(m0 + lm) * 1024 + lk;
    const bf16_t* bq = xp + (size_t)(b * 130 + tbase + lm) * 1024 + lk;
    #pragma unroll
    for (int k = 0; k < 32; ++k) {
        bf16x8 a0  = *(const bf16x8*)(aq + k * 32);
        bf16x8 a1  = *(const bf16x8*)(aq + 1048576 + k * 32);
        bf16x8 a2  = *(const bf16x8*)(aq + 2097152 + k * 32);
        bf16x8 b00 = *(const bf16x8*)(bq + k * 32);
        bf16x8 b01 = *(const bf16x8*)(bq + 1024 + k * 32);
        bf16x8 b02 = *(const bf16x8*)(bq + 2048 + k * 32);
        bf16x8 b10 = *(const bf16x8*)(bq + 16384 + k * 32);
        bf16x8 b11 = *(const bf16x8*)(bq + 17408 + k * 32);
        bf16x8 b12 = *(const bf16x8*)(bq + 18432 + k * 32);
        acc0 = __builtin_amdgcn_mfma_f32_16x16x32_bf16(a0, b00, acc0, 0, 0, 0);
        acc1 = __builtin_amdgcn_mfma_f32_16x16x32_bf16(a0, b10, acc1, 0, 0, 0);
        acc0 = __builtin_amdgcn_mfma_f32_16x16x32_bf16(a1, b01, acc0, 0, 0, 0);
        acc1 = __builtin_amdgcn_mfma_f32_16x16x32_bf16(a1, b11, acc1, 0, 0, 0);
        acc0 = __builtin_amdgcn_mfma_f32_16x16x32_bf16(a2, b02, acc0, 0, 0, 0);
        acc1 = __builtin_amdgcn_mfma_f32_16x16x32_bf16(a2, b12, acc1, 0, 0, 0);
    }
}

// 128x128 LDS-staged GEMM block: A = W^T panel (d rows), B = activation
// panel (bt/a rows), K=1024 in steps of 64. 8 waves as 4(row)x2(d); wave
// computes 32 rows x 64 d. LDS padded [128][72] => 2-way (free) banking.
__device__ __forceinline__ void gemm_tile_block(
    const bf16_t* __restrict__ At, const bf16_t* __restrict__ Bm,
    int d0b, int m0b, int tid,
    bf16_t (*As)[72], bf16_t (*Bs)[72], f32x4 acc[4][2])
{
    const int srow = tid >> 2, scol = (tid & 3) * 16;
    const int l = tid & 63;
    const int lm = l & 15, lk = (l >> 4) * 8;
    const int wv = tid >> 6;
    const int wrow = (wv & 3) * 32, wd = (wv >> 2) * 64;
    const bf16_t* as = At + (size_t)(d0b + srow) * 1024 + scol;
    const bf16_t* bs = Bm + (size_t)(m0b + srow) * 1024 + scol;
    for (int kc = 0; kc < 1024; kc += 64) {
        bf16x8 va0 = *(const bf16x8*)(as + kc);
        bf16x8 va1 = *(const bf16x8*)(as + kc + 8);
        bf16x8 vb0 = *(const bf16x8*)(bs + kc);
        bf16x8 vb1 = *(const bf16x8*)(bs + kc + 8);
        *(bf16x8*)&As[srow][scol] = va0;
        *(bf16x8*)&As[srow][scol + 8] = va1;
        *(bf16x8*)&Bs[srow][scol] = vb0;
        *(bf16x8*)&Bs[srow][scol + 8] = vb1;
        __syncthreads();
        #pragma unroll
        for (int cc = 0; cc < 2; ++cc) {
            bf16x8 bfr0 = *(const bf16x8*)&Bs[wrow + lm][cc * 32 + lk];
            bf16x8 bfr1 = *(const bf16x8*)&Bs[wrow + 16 + lm][cc * 32 + lk];
            #pragma unroll
            for (int mt = 0; mt < 4; ++mt) {
                bf16x8 af = *(const bf16x8*)&As[wd + mt * 16 + lm][cc * 32 + lk];
                acc[mt][0] = __builtin_amdgcn_mfma_f32_16x16x32_bf16(af, bfr0, acc[mt][0], 0, 0, 0);
                acc[mt][1] = __builtin_amdgcn_mfma_f32_16x16x32_bf16(af, bfr1, acc[mt][1], 0, 0, 0);
            }
        }
        __syncthreads();
    }
}

// ---------------------------------------------------------------------------
// P2: blocks [0,64) conv1 (16ch x 256bt, 8 waves, no LDS);
//     [64,80) tp gemm 128x128; [80,144) ap gemm 128x128.
// ---------------------------------------------------------------------------
__global__ __launch_bounds__(512) void p2_k(
    const bf16_t* __restrict__ wc1, const bf16_t* __restrict__ xp0,
    const float* __restrict__ d_b1, bf16_t* __restrict__ xp1,
    float* __restrict__ bstat1,
    const bf16_t* __restrict__ text_bf, const bf16_t* __restrict__ w1topT,
    const float* __restrict__ a_b1, f16_t* __restrict__ tp,
    const bf16_t* __restrict__ audio_bf, const bf16_t* __restrict__ w1botT,
    f16_t* __restrict__ apT4)
{
    __shared__ bf16_t As[128][72];
    __shared__ bf16_t Bs[128][72];
    const int bid = blockIdx.x;
    const int tid = threadIdx.x;
    const int wv = tid >> 6, l = tid & 63;
    const int lm = l & 15, lh = l >> 4;
    if (bid < 64) {
        // ---- conv1: ch group = bid, wave wv owns bt [wv*32, wv*32+32) ----
        const int m0 = bid * 16;
        const int b = wv >> 2, tbase = (wv & 3) * 32;
        f32x4 acc0 = (f32x4)(0.0f), acc1 = (f32x4)(0.0f);
        conv_mfma_full(wc1, xp0, m0, b, tbase, l, acc0, acc1);
        float4 bv = *(const float4*)&d_b1[m0 + lh * 4];
        float s = 0.f, q = 0.f;
        #pragma unroll
        for (int t2 = 0; t2 < 2; ++t2) {
            f32x4 a = t2 ? acc1 : acc0;
            bf16x4 o4;
            #pragma unroll
            for (int r = 0; r < 4; ++r) {
                float v = fmaxf(a[r] + ((const float*)&bv)[r], 0.f);
                s += v; q += v * v;
                o4[r] = (bf16_t)v;
            }
            const int bt = tbase + t2 * 16 + lm;
            *(bf16x4*)&xp1[(size_t)(b * 130 + 1 + bt) * 1024 + m0 + lh * 4] = o4;
        }
        s = wave_red_add(s); q = wave_red_add(q);
        if (l == 0) {
            const int idx = b * 256 + bid * 4 + (wv & 3);
            bstat1[idx * 2] = s; bstat1[idx * 2 + 1] = q;
        }
    } else {
        const int is_tp = (bid < 80) ? 1 : 0;
        int d0b, m0b;
        const bf16_t *At, *Bm;
        if (is_tp) {
            const int u = bid - 64;              // 16: 2 bt-blocks x 8 d-blocks
            m0b = (u & 1) * 128; d0b = (u >> 1) * 128;
            At = w1topT; Bm = text_bf;
        } else {
            const int u = bid - 80;              // 64: 8 a-blocks x 8 d-blocks
            m0b = (u & 7) * 128; d0b = (u >> 3) * 128;
            At = w1botT; Bm = audio_bf;
        }
        f32x4 acc[4][2];
        #pragma unroll
        for (int mt = 0; mt < 4; ++mt) { acc[mt][0] = (f32x4)(0.0f); acc[mt][1] = (f32x4)(0.0f); }
        gemm_tile_block(At, Bm, d0b, m0b, tid, As, Bs, acc);
        const int wrow = (wv & 3) * 32, wd = (wv >> 2) * 64;
        if (is_tp) {
            #pragma unroll
            for (int mt = 0; mt < 4; ++mt) {
                const int d = d0b + wd + mt * 16 + lh * 4;
                float4 bv = *(const float4*)&a_b1[d];
                #pragma unroll
                for (int nt = 0; nt < 2; ++nt) {
                    const int bt = m0b + wrow + nt * 16 + lm;
                    f16x4 v;
                    #pragma unroll
                    for (int r = 0; r < 4; ++r)
                        v[r] = (f16_t)(acc[mt][nt][r] + ((const float*)&bv)[r]);
                    *(f16x4*)&tp[(size_t)bt * 1024 + d] = v;
                }
            }
        } else {
            #pragma unroll
            for (int mt = 0; mt < 4; ++mt) {
                const int hq = (d0b + wd + mt * 16 + lh * 4) >> 2;
                #pragma unroll
                for (int nt = 0; nt < 2; ++nt) {
                    const int aa = m0b + wrow + nt * 16 + lm;
                    const int bb = aa >> 9, al = aa & 511;
                    f16x4 v;
                    #pragma unroll
                    for (int r = 0; r < 4; ++r) v[r] = (f16_t)acc[mt][nt][r];
                    *(f16x4*)&apT4[((size_t)hq * 1024 + bb * 512 + al) * 4] = v;
                }
            }
        }
    }
}

// ---------------------------------------------------------------------------
// P3: blocks [0,64) conv2 (GN1 folded, per-wave stat reduce, no LDS);
//     [64,192) logits (8 bt rows x 512 a per block).
// ---------------------------------------------------------------------------
__device__ __forceinline__ float dot2_acc(f16x2 x, f16x2 w, float acc) {
#if __has_builtin(__builtin_amdgcn_fdot2)
    return __builtin_amdgcn_fdot2(x, w, acc, false);
#else
    return acc + (float)x[0] * (float)w[0] + (float)x[1] * (float)w[1];
#endif
}

__global__ __launch_bounds__(512) void p3_k(
    const bf16_t* __restrict__ wc2, const bf16_t* __restrict__ xp1,
    const float* __restrict__ d_b2, bf16_t* __restrict__ y2,
    float* __restrict__ bstat2, const float* __restrict__ bstat1,
    const float* __restrict__ SgF, const float* __restrict__ SbF,
    const float* __restrict__ Sg3, const float* __restrict__ Sb3,
    const f16_t* __restrict__ tp, const f16_t* __restrict__ apT4,
    const f16_t* __restrict__ w2f, float* __restrict__ lp)
{
    const int bid = blockIdx.x;
    const int tid = threadIdx.x;
    if (bid < 64) {
        const int wv = tid >> 6, l = tid & 63;
        const int lm = l & 15, lh = l >> 4;
        const int m0 = bid * 16;
        const int b = wv >> 2, tbase = (wv & 3) * 32;
        f32x4 acc0 = (f32x4)(0.0f), acc1 = (f32x4)(0.0f);
        conv_mfma_full(wc2, xp1, m0, b, tbase, l, acc0, acc1);
        // per-wave GN1 stat reduce (256 (s,q) pairs = 128 float4)
        float s0, q0;
        {
            const float4* bp = (const float4*)bstat1 + (size_t)b * 128;
            float4 p0 = bp[l * 2], p1 = bp[l * 2 + 1];
            s0 = p0.x + p0.z + p1.x + p1.z;
            q0 = p0.y + p0.w + p1.y + p1.w;
        }
        s0 = wave_red_add(s0); q0 = wave_red_add(q0);
        const float mu = s0 * (1.f / 131072.f);
        const float rsig = rsqrtf(q0 * (1.f / 131072.f) - mu * mu + EPSV);
        float4 bv = *(const float4*)&d_b2[m0 + lh * 4];
        float4 gF = *(const float4*)&SgF[m0 + lh * 4];
        float4 bF = *(const float4*)&SbF[m0 + lh * 4];
        float s = 0.f, q = 0.f;
        #pragma unroll
        for (int t2 = 0; t2 < 2; ++t2) {
            f32x4 a = t2 ? acc1 : acc0;
            const int bt = tbase + t2 * 16 + lm;
            const bool e0 = (bt == 0), e1 = (bt == 127);
            bf16x4 o4;
            #pragma unroll
            for (int r = 0; r < 4; ++r) {
                const int o = m0 + lh * 4 + r;
                float sg = ((const float*)&gF)[r], sb = ((const float*)&bF)[r];
                if (e0) { sg -= Sg3[o * 3];     sb -= Sb3[o * 3]; }
                if (e1) { sg -= Sg3[o * 3 + 2]; sb -= Sb3[o * 3 + 2]; }
                float v = fmaxf(rsig * a[r] + sb - mu * rsig * sg + ((const float*)&bv)[r], 0.f);
                s += v; q += v * v;
                o4[r] = (bf16_t)v;
            }
            *(bf16x4*)&y2[(size_t)(b * 128 + bt) * 1024 + m0 + lh * 4] = o4;
        }
        s = wave_red_add(s); q = wave_red_add(q);
        if (l == 0) {
            const int idx = b * 256 + bid * 4 + (wv & 3);
            bstat2[idx * 2] = s; bstat2[idx * 2 + 1] = q;
        }
    } else {
        const int lb = bid - 64;                        // 128 blocks
        const int hc = lb >> 5, btp = lb & 31;          // 4 hc x 32 btp
        const int bt0 = btp * 8;
        const int b = bt0 >> 7;
        const int a = tid;                              // 0..511
        const f16_t* tpr = tp + (size_t)bt0 * 1024 + hc * 256;   // uniform
        const f16_t* w2r = w2f + hc * 256;
        const f16_t* apc = apT4 + ((size_t)(hc * 64) * 1024 + b * 512 + a) * 4;
        float acc[8] = {0.f, 0.f, 0.f, 0.f, 0.f, 0.f, 0.f, 0.f};
        const f16x2 zero = (f16x2)(f16_t)0.0f;
        #pragma unroll 2
        for (int hq = 0; hq < 64; hq += 2) {            // 8 h per iter
            f16x4 a0 = *(const f16x4*)(apc + (size_t)hq * 4096);
            f16x4 a1 = *(const f16x4*)(apc + (size_t)(hq + 1) * 4096);
            f16x4 w0 = *(const f16x4*)&w2r[hq * 4];
            f16x4 w1 = *(const f16x4*)&w2r[hq * 4 + 4];
            #pragma unroll
            for (int r = 0; r < 8; ++r) {
                f16x4 t0 = *(const f16x4*)&tpr[r * 1024 + hq * 4];
                f16x4 t1 = *(const f16x4*)&tpr[r * 1024 + hq * 4 + 4];
                f16x2 p;
                p = __builtin_elementwise_max((f16x2){t0[0] + a0[0], t0[1] + a0[1]}, zero);
                acc[r] = dot2_acc(p, (f16x2){w0[0], w0[1]}, acc[r]);
                p = __builtin_elementwise_max((f16x2){t0[2] + a0[2], t0[3] + a0[3]}, zero);
                acc[r] = dot2_acc(p, (f16x2){w0[2], w0[3]}, acc[r]);
                p = __builtin_elementwise_max((f16x2){t1[0] + a1[0], t1[1] + a1[1]}, zero);
                acc[r] = dot2_acc(p, (f16x2){w1[0], w1[1]}, acc[r]);
                p = __builtin_elementwise_max((f16x2){t1[2] + a1[2], t1[3] + a1[3]}, zero);
                acc[r] = dot2_acc(p, (f16x2){w1[2], w1[3]}, acc[r]);
            }
        }
        float* dst = lp + (size_t)(hc * 256 + bt0) * 512 + a;
        #pragma unroll
        for (int r = 0; r < 8; ++r) dst[(size_t)r * 512] = acc[r];
    }
}

// reduce 256 (s,q) pairs for batch b from bstat (block-level, 512 threads).
__device__ __forceinline__ void reduce_bstat(
    const float* __restrict__ bstat, int b, int tid,
    float* sr, float* sq, float& mu, float& rsig)
{
    const int lane = tid & 63, wid = tid >> 6;
    float s = 0.f, q = 0.f;
    if (tid < 256) {
        float2 v = ((const float2*)bstat)[b * 256 + tid];
        s = v.x; q = v.y;
    }
    #pragma unroll
    for (int off = 32; off > 0; off >>= 1) {
        s += __shfl_xor(s, off);
        q += __shfl_xor(q, off);
    }
    if (lane == 0) { sr[wid] = s; sq[wid] = q; }
    __syncthreads();
    float ts = 0.f, tq = 0.f;
    #pragma unroll
    for (int i = 0; i < 8; ++i) { ts += sr[i]; tq += sq[i]; }
    const float cnt = 131072.f;
    mu = ts / cnt;
    const float var = tq / cnt - mu * mu;
    rsig = rsqrtf(var + EPSV);
}

// ---------------------------------------------------------------------------
// combine: blocks [0,256): sum lp chunks + bias + monotonic, softmax -> out.
//          blocks [256,288): conv3 + GN2 (reduced from bstat2) + softplus.
// ---------------------------------------------------------------------------
__global__ __launch_bounds__(512) void combine_k(
    const float* __restrict__ lp, const float* __restrict__ b2,
    const bf16_t* __restrict__ y2, const float* __restrict__ bstat2,
    const float* __restrict__ g, const float* __restrict__ bet,
    const float* __restrict__ w3, const float* __restrict__ b3,
    float* __restrict__ out)
{
    __shared__ float redm[8], redsum[8];
    const int bid = blockIdx.x;
    const int tid = threadIdx.x;
    if (bid < 256) {
        const int bt = bid, t = bt & 127;
        const int a = tid;
        const int lane = a & 63, wid = a >> 6;
        const size_t base = (size_t)bt * 512 + a;
        float v = lp[base] + lp[131072 + base] + lp[262144 + base] + lp[393216 + base];
        v += b2[0] - 0.1f * fabsf((float)a - 4.0f * (float)t);
        float m = v;
        #pragma unroll
        for (int off = 32; off > 0; off >>= 1) m = fmaxf(m, __shfl_xor(m, off));
        if (lane == 0) redm[wid] = m;
        __syncthreads();
        float M = redm[0];
        #pragma unroll
        for (int i = 1; i < 8; ++i) M = fmaxf(M, redm[i]);
        const float e = expf(v - M);
        float s = e;
        #pragma unroll
        for (int off = 32; off > 0; off >>= 1) s += __shfl_xor(s, off);
        if (lane == 0) redsum[wid] = s;
        __syncthreads();
        float S = redsum[0];
        #pragma unroll
        for (int i = 1; i < 8; ++i) S += redsum[i];
        out[(size_t)bt * 512 + a] = e * (1.0f / S);
    } else {
        // conv3 + GN2-fold + softplus; mu/var reduced from conv2 partials.
        const int cb = bid - 256;              // 0..31, bt [cb*8, cb*8+8)
        const int b = (cb * 8) >> 7;
        float mu, rsig;
        reduce_bstat(bstat2, b, tid, redm, redsum, mu, rsig);
        const int lane = tid & 63, w = tid >> 6;
        const int bt = cb * 8 + w;
        const bf16_t* row = y2 + (size_t)bt * 1024 + lane * 16;
        float s1 = 0.f, s2 = 0.f, s3 = 0.f;
        #pragma unroll
        for (int c = 0; c < 2; ++c) {
            bf16x8 yv = *(const bf16x8*)(row + c * 8);
            #pragma unroll
            for (int j = 0; j < 8; ++j) {
                const int i = lane * 16 + c * 8 + j;
                const float gw = g[i] * w3[i];
                s1 += gw * (float)yv[j];
                s2 += gw;
                s3 += bet[i] * w3[i];
            }
        }
        #pragma unroll
        for (int off = 32; off > 0; off >>= 1) {
            s1 += __shfl_xor(s1, off);
            s2 += __shfl_xor(s2, off);
            s3 += __shfl_xor(s3, off);
        }
        if (lane == 0) {
            const float t = rsig * (s1 - mu * s2) + s3 + b3[0];
            out[131072 + bt] = fmaxf(t, 0.f) + log1pf(expf(-fabsf(t)));
        }
    }
}

extern "C" void kernel_launch(void* const* d_in, const int* in_sizes, int n_in,
                              void* d_out, int out_size, void* d_ws, size_t ws_size,
                              hipStream_t stream) {
    const float* text   = (const float*)d_in[0];
    const float* audio  = (const float*)d_in[1];
    const float* a_w1   = (const float*)d_in[2];
    const float* a_b1   = (const float*)d_in[3];
    const float* a_w2   = (const float*)d_in[4];
    const float* a_b2   = (const float*)d_in[5];
    const float* d_w1   = (const float*)d_in[6];
    const float* d_b1   = (const float*)d_in[7];
    const float* gn1_g  = (const float*)d_in[8];
    const float* gn1_b  = (const float*)d_in[9];
    const float* d_w2   = (const float*)d_in[10];
    const float* d_b2   = (const float*)d_in[11];
    const float* gn2_g  = (const float*)d_in[12];
    const float* gn2_b  = (const float*)d_in[13];
    const float* d_w3   = (const float*)d_in[14];
    const float* d_b3   = (const float*)d_in[15];

    char* ws = (char*)d_ws;
    float* outf = (float*)d_out;

    bf16_t* text_bf  = (bf16_t*)(ws + OFF_TEXTBF);
    bf16_t* audio_bf = (bf16_t*)(ws + OFF_AUDIOBF);
    bf16_t* w1topT   = (bf16_t*)(ws + OFF_W1TOP);
    bf16_t* w1botT   = (bf16_t*)(ws + OFF_W1BOT);
    bf16_t* wc1      = (bf16_t*)(ws + OFF_WC1);
    bf16_t* wc2      = (bf16_t*)(ws + OFF_WC2);
    f16_t*  tp       = (f16_t*) (ws + OFF_TP);
    f16_t*  w2f      = (f16_t*) (ws + OFF_W2F);
    f16_t*  apT4     = (f16_t*) (ws + OFF_APT);
    bf16_t* xp0      = (bf16_t*)(ws + OFF_XP0);
    bf16_t* xp1      = (bf16_t*)(ws + OFF_XP1);
    bf16_t* y2       = (bf16_t*)(ws + OFF_Y2);
    float*  bstat1   = (float*) (ws + OFF_BST1);
    float*  bstat2   = (float*) (ws + OFF_BST2);
    float*  lp       = (float*) (ws + OFF_LP);
    float*  Sg3     = (float*) (ws + OFF_SG);
    float*  Sb3     = (float*) (ws + OFF_SB);
    float*  SgFp    = (float*) (ws + OFF_SGF);
    float*  SbFp    = (float*) (ws + OFF_SBF);

    // 1: prep (cvt activations, w1 transpose, conv weights + sums, pads, w2f)
    prep_k<<<dim3(5377), 256, 0, stream>>>(text, audio, a_w1, d_w1, d_w2, a_w2,
                                           gn1_g, gn1_b,
                                           text_bf, xp0, audio_bf, w1topT, w1botT,
                                           wc1, wc2, xp1, w2f, Sg3, Sb3,
                                           SgFp, SbFp);
    // 2: conv1 (64) ∥ tp gemm (16) ∥ ap gemm (64) — 144 x 512 thr
    p2_k<<<dim3(144), 512, 0, stream>>>(wc1, xp0, d_b1, xp1, bstat1,
                                        text_bf, w1topT, a_b1, tp,
                                        audio_bf, w1botT, apT4);
    // 3: conv2 (64, GN1 folded) ∥ logits (128) — 192 x 512 thr
    p3_k<<<dim3(192), 512, 0, stream>>>(wc2, xp1, d_b2, y2, bstat2, bstat1,
                                        SgFp, SbFp, Sg3, Sb3, tp, apT4, w2f, lp);
    // 4: combine+softmax -> alignment; conv3+GN2(reduced)+softplus -> durations
    combine_k<<<dim3(288), 512, 0, stream>>>(lp, a_b2, y2, bstat2,
                                             gn2_g, gn2_b, d_w3, d_b3, outf);
}